// Round 8
// baseline (237.010 us; speedup 1.0000x reference)
//
#include <hip/hip_runtime.h>
#include <hip/hip_fp16.h>
#include <math.h>

// ---------------- problem constants ----------------
#define NB    256
#define NTOKP 197
#define NTOK  196
#define NC    768
#define NHID  192
#define NH    14
#define NVF   8        // rfft cols = 14/2+1
#define CHT   64       // channels per tile
#define NTILE 12       // 768/64
#define HPB   4        // hiddens per block in k_mlp1
#define NGRP  (NHID / HPB)  // 48 blocks

// twiddles (compile-time folded under full unroll)
constexpr float CT14[14] = {
    1.0f, 0.9009688679024191f, 0.6234898018587336f, 0.22252093395631445f,
    -0.22252093395631434f, -0.6234898018587335f, -0.9009688679024191f, -1.0f,
    -0.9009688679024191f, -0.6234898018587335f, -0.22252093395631434f,
    0.22252093395631445f, 0.6234898018587336f, 0.9009688679024191f};
constexpr float ST14[14] = {
    0.0f, 0.4338837391175581f, 0.7818314824680298f, 0.9749279121818236f,
    0.9749279121818236f, 0.7818314824680299f, 0.43388373911755823f, 0.0f,
    -0.43388373911755823f, -0.7818314824680299f, -0.9749279121818236f,
    -0.9749279121818236f, -0.7818314824680298f, -0.4338837391175581f};

__device__ __forceinline__ unsigned int pack_h2(float a, float b) {
  __half2 h = __floats2half2_rn(a, b);
  return *(unsigned int*)&h;
}
__device__ __forceinline__ float2 unpack_h2(unsigned int p) {
  __half2 h = *(__half2*)&p;
  return __half22float2(h);
}

// ---------------- K1: LayerNorm stats per (b, token) -> float2(mean, rstd) ----
__global__ __launch_bounds__(256) void k_stats(const float* __restrict__ x,
                                               float2* __restrict__ msv) {
  int row = blockIdx.x * 4 + (threadIdx.x >> 6);
  int lane = threadIdx.x & 63;
  if (row >= NB * NTOK) return;
  int b = row / NTOK, t = row - b * NTOK;
  const float4* p = (const float4*)(x + ((size_t)b * NTOKP + 1 + t) * NC);
  float s = 0.f, ss = 0.f;
#pragma unroll
  for (int k = 0; k < 3; ++k) {
    float4 v = p[lane + k * 64];
    s += v.x + v.y + v.z + v.w;
    ss += v.x * v.x + v.y * v.y + v.z * v.z + v.w * v.w;
  }
#pragma unroll
  for (int off = 32; off; off >>= 1) {
    s += __shfl_down(s, off);
    ss += __shfl_down(ss, off);
  }
  if (lane == 0) {
    float m = s * (1.f / NC);
    float var = ss * (1.f / NC) - m * m;
    msv[row] = make_float2(m, rsqrtf(var + 1e-5f));
  }
}

// ---------------- K2: forward DFT + energy (transposed out) ----------------
__global__ __launch_bounds__(256) void k_fwd(const float* __restrict__ x,
                                             const float* __restrict__ gamma,
                                             const float* __restrict__ beta,
                                             const float2* __restrict__ msv,
                                             float* __restrict__ energy_t) {
  __shared__ unsigned int A[NH * NVF * CHT];  // [i][v][c] packed fp16 (re,im) 28.7KB
  __shared__ float2 ms[NTOK];
  __shared__ float esum[256];
  int b = blockIdx.y, c0 = blockIdx.x * CHT, tid = threadIdx.x;
  int c = tid & 63, w = tid >> 6;

  for (int k = tid; k < NTOK; k += 256) ms[k] = msv[b * NTOK + k];
  float g = gamma[c0 + c], be = beta[c0 + c];
  __syncthreads();

  // stage A: per (c,i): A[i,v] = sum_j xn[i,j] e^{-2pi i v j/14}
#pragma unroll 1
  for (int i = w; i < NH; i += 4) {
    const float* xr = x + ((size_t)b * NTOKP + 1 + i * NH) * NC + c0 + c;
    float xn_[NH];
#pragma unroll
    for (int j = 0; j < NH; ++j) {
      float2 m = ms[i * NH + j];
      xn_[j] = (xr[(size_t)j * NC] - m.x) * m.y * g + be;
    }
    float ar[NVF] = {}, ai[NVF] = {};
#pragma unroll
    for (int j = 0; j < NH; ++j) {
#pragma unroll
      for (int v = 0; v < NVF; ++v) {
        ar[v] = fmaf(xn_[j], CT14[(v * j) % 14], ar[v]);
        ai[v] = fmaf(-xn_[j], ST14[(v * j) % 14], ai[v]);
      }
    }
#pragma unroll
    for (int v = 0; v < NVF; ++v) A[(i * NVF + v) * CHT + c] = pack_h2(ar[v], ai[v]);
  }
  __syncthreads();

  // stage B: per (c, v in {2w,2w+1}): S[u,v] over u=0..13, accumulate energy
  float part = 0.f;
#pragma unroll 1
  for (int vv = 0; vv < 2; ++vv) {
    int v = w * 2 + vv;
    const unsigned int* Ac = A + v * CHT + c;
    float sr[NH], si[NH];
#pragma unroll
    for (int u = 0; u < NH; ++u) { sr[u] = 0.f; si[u] = 0.f; }
#pragma unroll
    for (int i = 0; i < NH; ++i) {
      float2 a = unpack_h2(Ac[i * NVF * CHT]);
#pragma unroll
      for (int u = 0; u < NH; ++u) {
        int idx = (u * i) % 14;
        sr[u] = fmaf(a.x, CT14[idx], fmaf(a.y, ST14[idx], sr[u]));
        si[u] = fmaf(a.y, CT14[idx], fmaf(-a.x, ST14[idx], si[u]));
      }
    }
#pragma unroll
    for (int u = 0; u < NH; ++u) {
      float m2 = fmaf(sr[u], sr[u], si[u] * si[u]);
      part += __logf(1.f + __builtin_amdgcn_sqrtf(m2) * (1.f / 14.f));
    }
    if (w == 0 && vv == 0) {  // remove DC bin contribution (ref FFTs zero-mean input)
      part -= __logf(1.f + fabsf(sr[0]) * (1.f / 14.f));
    }
  }
  esum[tid] = part;
  __syncthreads();
  if (w == 0) {
    float e = esum[c] + esum[c + 64] + esum[c + 128] + esum[c + 192];
    energy_t[(size_t)(c0 + c) * NB + b] = e * (1.f / 112.f);
  }
}

// ---------------- K3a: MLP layer1+gelu+layer2-partials ----------------
// 48 blocks x 256 thr. lane = batch. Block owns 4 hiddens -> w1 reads are
// wave-uniform (s_load); each w1 element read ONCE device-wide (590KB total).
__global__ __launch_bounds__(256) void k_mlp1(const float* __restrict__ et,
                                              const float* __restrict__ w1,
                                              const float* __restrict__ b1,
                                              const float* __restrict__ w2,
                                              float* __restrict__ partial) {
  int h0 = blockIdx.x * HPB;
  int bb = threadIdx.x;  // batch
  float acc[HPB] = {};
#pragma unroll 8
  for (int cc = 0; cc < NC; ++cc) {
    float e = et[(size_t)cc * NB + bb];   // coalesced vector load
#pragma unroll
    for (int k = 0; k < HPB; ++k)         // wave-uniform -> scalar loads
      acc[k] = fmaf(e, w1[(size_t)cc * NHID + h0 + k], acc[k]);
  }
  float p0 = 0.f, p1 = 0.f;
#pragma unroll
  for (int k = 0; k < HPB; ++k) {
    float a = acc[k] + b1[h0 + k];
    float ge = 0.5f * a * (1.f + erff(a * 0.70710678118654752f));  // exact gelu
    p0 = fmaf(ge, w2[2 * (h0 + k)], p0);
    p1 = fmaf(ge, w2[2 * (h0 + k) + 1], p1);
  }
  partial[(size_t)(2 * blockIdx.x) * NB + bb] = p0;
  partial[(size_t)(2 * blockIdx.x + 1) * NB + bb] = p1;
}

// ---------------- K3b: reduce partials -> m2s ----------------
__global__ __launch_bounds__(256) void k_final(const float* __restrict__ partial,
                                               const float* __restrict__ b2,
                                               float* __restrict__ m2s) {
  int bb = threadIdx.x;
  float p0 = b2[0], p1 = b2[1];
#pragma unroll
  for (int g = 0; g < NGRP; ++g) {
    p0 += partial[(size_t)(2 * g) * NB + bb];
    p1 += partial[(size_t)(2 * g + 1) * NB + bb];
  }
  float muv = 9.899494936611665f / (1.f + expf(-p0));
  muv = fmaxf(muv, 1.f);
  float sp = (p1 > 20.f) ? p1 : log1pf(expf(p1));
  float sg = fmaxf(sp, 0.1f);
  m2s[bb] = 2.f * muv * muv * sg + 1e-6f;
}

// ---------------- K4: separable circulant filter + residual ----------------
// mask separable: exp(-(fy2[u]+fx2[v])/ms) = wexp[u]*wexp[v]
// filtered = K (x) K (x) xn  (mean path drops out: mask[0,0]=1 => K*const=const)
__global__ __launch_bounds__(256) void k_inv(const float* __restrict__ x,
                                             const float* __restrict__ gamma,
                                             const float* __restrict__ beta,
                                             const float2* __restrict__ msv,
                                             const float* __restrict__ m2s,
                                             const float* __restrict__ rscale,
                                             float* __restrict__ out) {
  __shared__ unsigned int T[NH * 7 * CHT];  // y[i][j'] fp16 pairs: 25KB
  __shared__ float2 ms[NTOK];
  __shared__ float wexp[NH];
  __shared__ float kc[NH];
  int b = blockIdx.y, c0 = blockIdx.x * CHT, tid = threadIdx.x;
  int c = tid & 63, w = tid >> 6;
  float rs = rscale[0];

  for (int k = tid; k < NTOK; k += 256) ms[k] = msv[b * NTOK + k];
  if (tid < CHT) {  // cls-token passthrough
    size_t idx = (size_t)b * NTOKP * NC + c0 + tid;
    out[idx] = x[idx];
  }
  float msb = m2s[b];
  if (tid < NH) {
    int f = (tid <= 7) ? tid : 14 - tid;
    wexp[tid] = __expf(-(float)(f * f) / msb);
  }
  __syncthreads();
  if (tid < NH) {
    float s = 0.f;
#pragma unroll
    for (int k = 0; k < NH; ++k) s = fmaf(wexp[k], CT14[(k * tid) % 14], s);
    kc[tid] = s * (1.f / 14.f);
  }
  float g = gamma[c0 + c], be = beta[c0 + c];
  __syncthreads();

  float kr[NH];
#pragma unroll
  for (int d = 0; d < NH; ++d) kr[d] = kc[d];

  // stage 1: per (c,i): y[i,j'] = sum_j xn[i,j]*kc[(j'-j)%14] -> T
#pragma unroll 1
  for (int i = w; i < NH; i += 4) {
    const float* xr = x + ((size_t)b * NTOKP + 1 + i * NH) * NC + c0 + c;
    float xn_[NH];
#pragma unroll
    for (int j = 0; j < NH; ++j) {
      float2 m = ms[i * NH + j];
      xn_[j] = (xr[(size_t)j * NC] - m.x) * m.y * g + be;
    }
#pragma unroll
    for (int jp = 0; jp < 7; ++jp) {
      float y0 = 0.f, y1 = 0.f;
#pragma unroll
      for (int j = 0; j < NH; ++j) {
        y0 = fmaf(xn_[j], kr[(2 * jp - j + 28) % 14], y0);
        y1 = fmaf(xn_[j], kr[(2 * jp + 1 - j + 28) % 14], y1);
      }
      T[(i * 7 + jp) * CHT + c] = pack_h2(y0, y1);
    }
  }
  __syncthreads();

  // stage 2: per (c,jq): z[i'] = sum_i y[i,jq]*kc[(i'-i)%14]; out = xv + rs*(z-xn)
#pragma unroll 1
  for (int jq = w; jq < NH; jq += 4) {
    int jp = jq >> 1, hi = jq & 1;
    float y[NH];
#pragma unroll
    for (int i = 0; i < NH; ++i) {
      float2 v = unpack_h2(T[(i * 7 + jp) * CHT + c]);
      y[i] = hi ? v.y : v.x;
    }
    const float* xr = x + ((size_t)b * NTOKP + 1 + jq) * NC + c0 + c;
    float* outr = out + ((size_t)b * NTOKP + 1 + jq) * NC + c0 + c;
#pragma unroll
    for (int ii = 0; ii < NH; ++ii) {
      float z = 0.f;
#pragma unroll
      for (int i = 0; i < NH; ++i) z = fmaf(y[i], kr[(ii - i + 28) % 14], z);
      float xv = xr[(size_t)ii * NH * NC];
      float2 m = ms[ii * NH + jq];
      float xn = (xv - m.x) * m.y * g + be;
      outr[(size_t)ii * NH * NC] = xv + rs * (z - xn);
    }
  }
}

extern "C" void kernel_launch(void* const* d_in, const int* in_sizes, int n_in,
                              void* d_out, int out_size, void* d_ws, size_t ws_size,
                              hipStream_t stream) {
  (void)in_sizes; (void)n_in; (void)out_size; (void)ws_size;
  const float* x      = (const float*)d_in[0];
  const float* gamma  = (const float*)d_in[1];
  const float* beta   = (const float*)d_in[2];
  const float* w1     = (const float*)d_in[3];
  const float* b1     = (const float*)d_in[4];
  const float* w2     = (const float*)d_in[5];
  const float* b2     = (const float*)d_in[6];
  const float* rscale = (const float*)d_in[7];
  float* out = (float*)d_out;

  char* wsb = (char*)d_ws;
  float2* msv     = (float2*)(wsb + 0);        //   401,408 B
  float* energy_t = (float*)(wsb + 401408);    //   786,432 B  [NC][NB]
  float* partial  = (float*)(wsb + 1187840);   //    98,304 B  [2*NGRP][NB]
  float* m2s      = (float*)(wsb + 1286144);   //     1,024 B

  k_stats<<<(NB * NTOK + 3) / 4, 256, 0, stream>>>(x, msv);
  k_fwd<<<dim3(NTILE, NB), 256, 0, stream>>>(x, gamma, beta, msv, energy_t);
  k_mlp1<<<NGRP, 256, 0, stream>>>(energy_t, w1, b1, w2, partial);
  k_final<<<1, 256, 0, stream>>>(partial, b2, m2s);
  k_inv<<<dim3(NTILE, NB), 256, 0, stream>>>(x, gamma, beta, msv, m2s, rscale,
                                             out);
}

// Round 9
// 167.218 us; speedup vs baseline: 1.4174x; 1.4174x over previous
//
#include <hip/hip_runtime.h>
#include <hip/hip_fp16.h>
#include <math.h>

// ---------------- problem constants ----------------
#define NB    256
#define NTOKP 197
#define NTOK  196
#define NC    768
#define NHID  192
#define NH    14
#define NVF   8        // rfft cols = 14/2+1
#define CHT   64       // channels per tile
#define NTILE 12       // 768/64
#define NCH   8        // C-chunks in k_mlp1
#define CCH   (NC / NCH)  // 96 channels per chunk

// twiddles (compile-time folded under full unroll)
constexpr float CT14[14] = {
    1.0f, 0.9009688679024191f, 0.6234898018587336f, 0.22252093395631445f,
    -0.22252093395631434f, -0.6234898018587335f, -0.9009688679024191f, -1.0f,
    -0.9009688679024191f, -0.6234898018587335f, -0.22252093395631434f,
    0.22252093395631445f, 0.6234898018587336f, 0.9009688679024191f};
constexpr float ST14[14] = {
    0.0f, 0.4338837391175581f, 0.7818314824680298f, 0.9749279121818236f,
    0.9749279121818236f, 0.7818314824680299f, 0.43388373911755823f, 0.0f,
    -0.43388373911755823f, -0.7818314824680299f, -0.9749279121818236f,
    -0.9749279121818236f, -0.7818314824680298f, -0.4338837391175581f};

__device__ __forceinline__ unsigned int pack_h2(float a, float b) {
  __half2 h = __floats2half2_rn(a, b);
  return *(unsigned int*)&h;
}
__device__ __forceinline__ float2 unpack_h2(unsigned int p) {
  __half2 h = *(__half2*)&p;
  return __half22float2(h);
}

// ---------------- K1: LayerNorm stats per (b, token) -> float2(mean, rstd) ----
__global__ __launch_bounds__(256) void k_stats(const float* __restrict__ x,
                                               float2* __restrict__ msv) {
  int row = blockIdx.x * 4 + (threadIdx.x >> 6);
  int lane = threadIdx.x & 63;
  if (row >= NB * NTOK) return;
  int b = row / NTOK, t = row - b * NTOK;
  const float4* p = (const float4*)(x + ((size_t)b * NTOKP + 1 + t) * NC);
  float s = 0.f, ss = 0.f;
#pragma unroll
  for (int k = 0; k < 3; ++k) {
    float4 v = p[lane + k * 64];
    s += v.x + v.y + v.z + v.w;
    ss += v.x * v.x + v.y * v.y + v.z * v.z + v.w * v.w;
  }
#pragma unroll
  for (int off = 32; off; off >>= 1) {
    s += __shfl_down(s, off);
    ss += __shfl_down(ss, off);
  }
  if (lane == 0) {
    float m = s * (1.f / NC);
    float var = ss * (1.f / NC) - m * m;
    msv[row] = make_float2(m, rsqrtf(var + 1e-5f));
  }
}

// ---------------- K2: forward DFT + energy ----------------
__global__ __launch_bounds__(256) void k_fwd(const float* __restrict__ x,
                                             const float* __restrict__ gamma,
                                             const float* __restrict__ beta,
                                             const float2* __restrict__ msv,
                                             float* __restrict__ energy) {
  __shared__ unsigned int A[NH * NVF * CHT];  // [i][v][c] packed fp16 (re,im) 28.7KB
  __shared__ float2 ms[NTOK];
  __shared__ float esum[256];
  int b = blockIdx.y, c0 = blockIdx.x * CHT, tid = threadIdx.x;
  int c = tid & 63, w = tid >> 6;

  for (int k = tid; k < NTOK; k += 256) ms[k] = msv[b * NTOK + k];
  float g = gamma[c0 + c], be = beta[c0 + c];
  __syncthreads();

  // stage A: per (c,i): A[i,v] = sum_j xn[i,j] e^{-2pi i v j/14}
#pragma unroll 1
  for (int i = w; i < NH; i += 4) {
    const float* xr = x + ((size_t)b * NTOKP + 1 + i * NH) * NC + c0 + c;
    float xn_[NH];
#pragma unroll
    for (int j = 0; j < NH; ++j) {
      float2 m = ms[i * NH + j];
      xn_[j] = (xr[(size_t)j * NC] - m.x) * m.y * g + be;
    }
    float ar[NVF] = {}, ai[NVF] = {};
#pragma unroll
    for (int j = 0; j < NH; ++j) {
#pragma unroll
      for (int v = 0; v < NVF; ++v) {
        ar[v] = fmaf(xn_[j], CT14[(v * j) % 14], ar[v]);
        ai[v] = fmaf(-xn_[j], ST14[(v * j) % 14], ai[v]);
      }
    }
#pragma unroll
    for (int v = 0; v < NVF; ++v) A[(i * NVF + v) * CHT + c] = pack_h2(ar[v], ai[v]);
  }
  __syncthreads();

  // stage B: per (c, v in {2w,2w+1}): S[u,v] over u=0..13, accumulate energy
  float part = 0.f;
#pragma unroll 1
  for (int vv = 0; vv < 2; ++vv) {
    int v = w * 2 + vv;
    const unsigned int* Ac = A + v * CHT + c;
    float sr[NH], si[NH];
#pragma unroll
    for (int u = 0; u < NH; ++u) { sr[u] = 0.f; si[u] = 0.f; }
#pragma unroll
    for (int i = 0; i < NH; ++i) {
      float2 a = unpack_h2(Ac[i * NVF * CHT]);
#pragma unroll
      for (int u = 0; u < NH; ++u) {
        int idx = (u * i) % 14;
        sr[u] = fmaf(a.x, CT14[idx], fmaf(a.y, ST14[idx], sr[u]));
        si[u] = fmaf(a.y, CT14[idx], fmaf(-a.x, ST14[idx], si[u]));
      }
    }
#pragma unroll
    for (int u = 0; u < NH; ++u) {
      float m2 = fmaf(sr[u], sr[u], si[u] * si[u]);
      part += __logf(1.f + __builtin_amdgcn_sqrtf(m2) * (1.f / 14.f));
    }
    if (w == 0 && vv == 0) {  // remove DC bin contribution (ref FFTs zero-mean input)
      part -= __logf(1.f + fabsf(sr[0]) * (1.f / 14.f));
    }
  }
  esum[tid] = part;
  __syncthreads();
  if (w == 0) {
    float e = esum[c] + esum[c + 64] + esum[c + 128] + esum[c + 192];
    energy[(size_t)b * NC + c0 + c] = e * (1.f / 112.f);
  }
}

// ---------------- K3a: MLP layer-1 partials. 2048 blocks for TLP ----------------
// block (chunk s, batch b), thread = hidden h. energy[b][cc] is block-uniform
// (s_load); w1[cc][h] coalesced across lanes. 8 blocks/CU hide cold-HBM latency.
__global__ __launch_bounds__(192) void k_mlp1(const float* __restrict__ energy,
                                              const float* __restrict__ w1,
                                              float* __restrict__ partial) {
  int s = blockIdx.x, b = blockIdx.y;
  int h = threadIdx.x;
  const float* ep = energy + (size_t)b * NC + s * CCH;
  const float* wp = w1 + (size_t)s * CCH * NHID + h;
  float acc = 0.f;
#pragma unroll 8
  for (int cc = 0; cc < CCH; ++cc)
    acc = fmaf(ep[cc], wp[(size_t)cc * NHID], acc);
  partial[((size_t)b * NCH + s) * NHID + h] = acc;
}

// ---------------- K3b: finalize MLP per batch ----------------
__global__ __launch_bounds__(192) void k_final(const float* __restrict__ partial,
                                               const float* __restrict__ b1,
                                               const float* __restrict__ w2,
                                               const float* __restrict__ b2,
                                               float* __restrict__ m2s) {
  __shared__ float2 sh[NHID];
  int b = blockIdx.x, h = threadIdx.x;
  float a = b1[h];
#pragma unroll
  for (int s = 0; s < NCH; ++s) a += partial[((size_t)b * NCH + s) * NHID + h];
  float ge = 0.5f * a * (1.f + erff(a * 0.70710678118654752f));  // exact gelu
  sh[h] = make_float2(ge * w2[2 * h], ge * w2[2 * h + 1]);
  __syncthreads();
  if (h < 64) {
    float p0 = sh[h].x + sh[h + 64].x + sh[h + 128].x;
    float p1 = sh[h].y + sh[h + 64].y + sh[h + 128].y;
#pragma unroll
    for (int off = 32; off; off >>= 1) {
      p0 += __shfl_down(p0, off);
      p1 += __shfl_down(p1, off);
    }
    if (h == 0) {
      float o0 = p0 + b2[0], o1 = p1 + b2[1];
      float muv = 9.899494936611665f / (1.f + expf(-o0));
      muv = fmaxf(muv, 1.f);
      float sp = (o1 > 20.f) ? o1 : log1pf(expf(o1));
      float sg = fmaxf(sp, 0.1f);
      m2s[b] = 2.f * muv * muv * sg + 1e-6f;
    }
  }
}

// ---------------- K4: separable circulant filter + residual ----------------
// mask separable: exp(-(fy2[u]+fx2[v])/ms) = wexp[u]*wexp[v]
// filtered = K (x) K (x) xn  (mean path drops out: mask[0,0]=1 => K*const=const)
__global__ __launch_bounds__(256) void k_inv(const float* __restrict__ x,
                                             const float* __restrict__ gamma,
                                             const float* __restrict__ beta,
                                             const float2* __restrict__ msv,
                                             const float* __restrict__ m2s,
                                             const float* __restrict__ rscale,
                                             float* __restrict__ out) {
  __shared__ unsigned int T[NH * 7 * CHT];  // y[i][j'] fp16 pairs: 25KB
  __shared__ float2 ms[NTOK];
  __shared__ float wexp[NH];
  __shared__ float kc[NH];
  int b = blockIdx.y, c0 = blockIdx.x * CHT, tid = threadIdx.x;
  int c = tid & 63, w = tid >> 6;
  float rs = rscale[0];

  for (int k = tid; k < NTOK; k += 256) ms[k] = msv[b * NTOK + k];
  if (tid < CHT) {  // cls-token passthrough
    size_t idx = (size_t)b * NTOKP * NC + c0 + tid;
    out[idx] = x[idx];
  }
  float msb = m2s[b];
  if (tid < NH) {
    int f = (tid <= 7) ? tid : 14 - tid;
    wexp[tid] = __expf(-(float)(f * f) / msb);
  }
  __syncthreads();
  if (tid < NH) {
    float s = 0.f;
#pragma unroll
    for (int k = 0; k < NH; ++k) s = fmaf(wexp[k], CT14[(k * tid) % 14], s);
    kc[tid] = s * (1.f / 14.f);
  }
  float g = gamma[c0 + c], be = beta[c0 + c];
  __syncthreads();

  float kr[NH];
#pragma unroll
  for (int d = 0; d < NH; ++d) kr[d] = kc[d];

  // stage 1: per (c,i): y[i,j'] = sum_j xn[i,j]*kc[(j'-j)%14] -> T
#pragma unroll 1
  for (int i = w; i < NH; i += 4) {
    const float* xr = x + ((size_t)b * NTOKP + 1 + i * NH) * NC + c0 + c;
    float xn_[NH];
#pragma unroll
    for (int j = 0; j < NH; ++j) {
      float2 m = ms[i * NH + j];
      xn_[j] = (xr[(size_t)j * NC] - m.x) * m.y * g + be;
    }
#pragma unroll
    for (int jp = 0; jp < 7; ++jp) {
      float y0 = 0.f, y1 = 0.f;
#pragma unroll
      for (int j = 0; j < NH; ++j) {
        y0 = fmaf(xn_[j], kr[(2 * jp - j + 28) % 14], y0);
        y1 = fmaf(xn_[j], kr[(2 * jp + 1 - j + 28) % 14], y1);
      }
      T[(i * 7 + jp) * CHT + c] = pack_h2(y0, y1);
    }
  }
  __syncthreads();

  // stage 2: per (c,jq): z[i'] = sum_i y[i,jq]*kc[(i'-i)%14]; out = xv + rs*(z-xn)
#pragma unroll 1
  for (int jq = w; jq < NH; jq += 4) {
    int jp = jq >> 1, hi = jq & 1;
    float y[NH];
#pragma unroll
    for (int i = 0; i < NH; ++i) {
      float2 v = unpack_h2(T[(i * 7 + jp) * CHT + c]);
      y[i] = hi ? v.y : v.x;
    }
    const float* xr = x + ((size_t)b * NTOKP + 1 + jq) * NC + c0 + c;
    float* outr = out + ((size_t)b * NTOKP + 1 + jq) * NC + c0 + c;
#pragma unroll
    for (int ii = 0; ii < NH; ++ii) {
      float z = 0.f;
#pragma unroll
      for (int i = 0; i < NH; ++i) z = fmaf(y[i], kr[(ii - i + 28) % 14], z);
      float xv = xr[(size_t)ii * NH * NC];
      float2 m = ms[ii * NH + jq];
      float xn = (xv - m.x) * m.y * g + be;
      outr[(size_t)ii * NH * NC] = xv + rs * (z - xn);
    }
  }
}

extern "C" void kernel_launch(void* const* d_in, const int* in_sizes, int n_in,
                              void* d_out, int out_size, void* d_ws, size_t ws_size,
                              hipStream_t stream) {
  (void)in_sizes; (void)n_in; (void)out_size; (void)ws_size;
  const float* x      = (const float*)d_in[0];
  const float* gamma  = (const float*)d_in[1];
  const float* beta   = (const float*)d_in[2];
  const float* w1     = (const float*)d_in[3];
  const float* b1     = (const float*)d_in[4];
  const float* w2     = (const float*)d_in[5];
  const float* b2     = (const float*)d_in[6];
  const float* rscale = (const float*)d_in[7];
  float* out = (float*)d_out;

  char* wsb = (char*)d_ws;
  float2* msv    = (float2*)(wsb + 0);        //   401,408 B
  float* energy  = (float*)(wsb + 401408);    //   786,432 B  [NB][NC]
  float* partial = (float*)(wsb + 1187840);   // 1,572,864 B  [NB][NCH][NHID]
  float* m2s     = (float*)(wsb + 2760704);   //     1,024 B

  k_stats<<<(NB * NTOK + 3) / 4, 256, 0, stream>>>(x, msv);
  k_fwd<<<dim3(NTILE, NB), 256, 0, stream>>>(x, gamma, beta, msv, energy);
  k_mlp1<<<dim3(NCH, NB), 192, 0, stream>>>(energy, w1, partial);
  k_final<<<NB, 192, 0, stream>>>(partial, b1, w2, b2, m2s);
  k_inv<<<dim3(NTILE, NB), 256, 0, stream>>>(x, gamma, beta, msv, m2s, rscale,
                                             out);
}

// Round 10
// 154.058 us; speedup vs baseline: 1.5384x; 1.0854x over previous
//
#include <hip/hip_runtime.h>
#include <hip/hip_fp16.h>
#include <math.h>

// ---------------- problem constants ----------------
#define NB    256
#define NTOKP 197
#define NTOK  196
#define NC    768
#define NHID  192
#define NH    14
#define NVF   8        // rfft cols = 14/2+1
#define CHT   64       // channels per tile
#define NTILE 12       // 768/64
#define NCH   8        // C-chunks in k_mlp1
#define CCH   (NC / NCH)  // 96 channels per chunk

// twiddles (compile-time folded under full unroll)
constexpr float CT14[14] = {
    1.0f, 0.9009688679024191f, 0.6234898018587336f, 0.22252093395631445f,
    -0.22252093395631434f, -0.6234898018587335f, -0.9009688679024191f, -1.0f,
    -0.9009688679024191f, -0.6234898018587335f, -0.22252093395631434f,
    0.22252093395631445f, 0.6234898018587336f, 0.9009688679024191f};
constexpr float ST14[14] = {
    0.0f, 0.4338837391175581f, 0.7818314824680298f, 0.9749279121818236f,
    0.9749279121818236f, 0.7818314824680299f, 0.43388373911755823f, 0.0f,
    -0.43388373911755823f, -0.7818314824680299f, -0.9749279121818236f,
    -0.9749279121818236f, -0.7818314824680298f, -0.4338837391175581f};

// ---------------- K1: LayerNorm stats per (b, token) -> float2(mean, rstd) ----
__global__ __launch_bounds__(256) void k_stats(const float* __restrict__ x,
                                               float2* __restrict__ msv) {
  int row = blockIdx.x * 4 + (threadIdx.x >> 6);
  int lane = threadIdx.x & 63;
  if (row >= NB * NTOK) return;
  int b = row / NTOK, t = row - b * NTOK;
  const float4* p = (const float4*)(x + ((size_t)b * NTOKP + 1 + t) * NC);
  float s = 0.f, ss = 0.f;
#pragma unroll
  for (int k = 0; k < 3; ++k) {
    float4 v = p[lane + k * 64];
    s += v.x + v.y + v.z + v.w;
    ss += v.x * v.x + v.y * v.y + v.z * v.z + v.w * v.w;
  }
#pragma unroll
  for (int off = 32; off; off >>= 1) {
    s += __shfl_down(s, off);
    ss += __shfl_down(ss, off);
  }
  if (lane == 0) {
    float m = s * (1.f / NC);
    float var = ss * (1.f / NC) - m * m;
    msv[row] = make_float2(m, rsqrtf(var + 1e-5f));
  }
}

// ---------------- K2: forward DFT + energy (packed-fp16 math) ----------------
__global__ __launch_bounds__(256) void k_fwd(const float* __restrict__ x,
                                             const float* __restrict__ gamma,
                                             const float* __restrict__ beta,
                                             const float2* __restrict__ msv,
                                             float* __restrict__ energy) {
  __shared__ __half2 A[NH * NVF * CHT];  // [i][v][c] {re,im} fp16  28.7KB
  __shared__ float2 ms[NTOK];
  __shared__ float esum[256];
  int b = blockIdx.y, c0 = blockIdx.x * CHT, tid = threadIdx.x;
  int c = tid & 63, w = tid >> 6;

  for (int k = tid; k < NTOK; k += 256) ms[k] = msv[b * NTOK + k];
  float g = gamma[c0 + c], be = beta[c0 + c];

  // twiddle pair tables (register-resident under full unroll)
  __half2 TW1[14], TW2[14];  // {cos, -sin}, {sin, cos}
#pragma unroll
  for (int k = 0; k < 14; ++k) {
    TW1[k] = __floats2half2_rn(CT14[k], -ST14[k]);
    TW2[k] = __floats2half2_rn(ST14[k], CT14[k]);
  }
  __syncthreads();

  // stage A: per (c,i): A[i,v] = sum_j xn[i,j] e^{-2pi i v j/14}
  // packed: {ar,ai} += {xn,xn} * {cos, -sin}
#pragma unroll 1
  for (int i = w; i < NH; i += 4) {
    const float* xr = x + ((size_t)b * NTOKP + 1 + i * NH) * NC + c0 + c;
    __half2 xh[NH];
#pragma unroll
    for (int j = 0; j < NH; ++j) {
      float2 m = ms[i * NH + j];
      xh[j] = __float2half2_rn((xr[(size_t)j * NC] - m.x) * m.y * g + be);
    }
    __half2 acc[NVF];
#pragma unroll
    for (int v = 0; v < NVF; ++v) acc[v] = __floats2half2_rn(0.f, 0.f);
#pragma unroll
    for (int j = 0; j < NH; ++j) {
#pragma unroll
      for (int v = 0; v < NVF; ++v)
        acc[v] = __hfma2(xh[j], TW1[(v * j) % 14], acc[v]);
    }
#pragma unroll
    for (int v = 0; v < NVF; ++v) A[(i * NVF + v) * CHT + c] = acc[v];
  }
  __syncthreads();

  // stage B: per (c, v in {2w,2w+1}): S[u] = {sr,si}, packed
  // {sr,si} += {ar,ar}*{ct,-st} + {ai,ai}*{st,ct}
  float part = 0.f;
#pragma unroll 1
  for (int vv = 0; vv < 2; ++vv) {
    int v = w * 2 + vv;
    const __half2* Ac = A + v * CHT + c;
    __half2 S[NH];
#pragma unroll
    for (int u = 0; u < NH; ++u) S[u] = __floats2half2_rn(0.f, 0.f);
#pragma unroll
    for (int i = 0; i < NH; ++i) {
      __half2 a = Ac[i * NVF * CHT];
      __half2 arr = __low2half2(a);   // {ar,ar}
      __half2 aii = __high2half2(a);  // {ai,ai}
#pragma unroll
      for (int u = 0; u < NH; ++u) {
        int k = (u * i) % 14;
        S[u] = __hfma2(arr, TW1[k], __hfma2(aii, TW2[k], S[u]));
      }
    }
#pragma unroll
    for (int u = 0; u < NH; ++u) {
      float2 s = __half22float2(S[u]);
      float m2 = fmaf(s.x, s.x, s.y * s.y);
      part += __logf(1.f + __builtin_amdgcn_sqrtf(m2) * (1.f / 14.f));
    }
    if (w == 0 && vv == 0) {  // remove DC bin contribution (zero-mean in ref)
      part -= __logf(1.f + fabsf(__low2float(S[0])) * (1.f / 14.f));
    }
  }
  esum[tid] = part;
  __syncthreads();
  if (w == 0) {
    float e = esum[c] + esum[c + 64] + esum[c + 128] + esum[c + 192];
    energy[(size_t)b * NC + c0 + c] = e * (1.f / 112.f);
  }
}

// ---------------- K3a: MLP layer-1 partials. 2048 blocks for TLP ----------------
__global__ __launch_bounds__(192) void k_mlp1(const float* __restrict__ energy,
                                              const float* __restrict__ w1,
                                              float* __restrict__ partial) {
  int s = blockIdx.x, b = blockIdx.y;
  int h = threadIdx.x;
  const float* ep = energy + (size_t)b * NC + s * CCH;
  const float* wp = w1 + (size_t)s * CCH * NHID + h;
  float acc = 0.f;
#pragma unroll 8
  for (int cc = 0; cc < CCH; ++cc)
    acc = fmaf(ep[cc], wp[(size_t)cc * NHID], acc);
  partial[((size_t)b * NCH + s) * NHID + h] = acc;
}

// ---------------- K3b: finalize MLP per batch ----------------
__global__ __launch_bounds__(192) void k_final(const float* __restrict__ partial,
                                               const float* __restrict__ b1,
                                               const float* __restrict__ w2,
                                               const float* __restrict__ b2,
                                               float* __restrict__ m2s) {
  __shared__ float2 sh[NHID];
  int b = blockIdx.x, h = threadIdx.x;
  float a = b1[h];
#pragma unroll
  for (int s = 0; s < NCH; ++s) a += partial[((size_t)b * NCH + s) * NHID + h];
  float ge = 0.5f * a * (1.f + erff(a * 0.70710678118654752f));  // exact gelu
  sh[h] = make_float2(ge * w2[2 * h], ge * w2[2 * h + 1]);
  __syncthreads();
  if (h < 64) {
    float p0 = sh[h].x + sh[h + 64].x + sh[h + 128].x;
    float p1 = sh[h].y + sh[h + 64].y + sh[h + 128].y;
#pragma unroll
    for (int off = 32; off; off >>= 1) {
      p0 += __shfl_down(p0, off);
      p1 += __shfl_down(p1, off);
    }
    if (h == 0) {
      float o0 = p0 + b2[0], o1 = p1 + b2[1];
      float muv = 9.899494936611665f / (1.f + expf(-o0));
      muv = fmaxf(muv, 1.f);
      float sp = (o1 > 20.f) ? o1 : log1pf(expf(o1));
      float sg = fmaxf(sp, 0.1f);
      m2s[b] = 2.f * muv * muv * sg + 1e-6f;
    }
  }
}

// ---------------- K4: separable circulant filter (packed fp16) + residual ----
// mask separable: exp(-(fy2[u]+fx2[v])/ms) = wexp[u]*wexp[v]
// filtered = K (x) K (x) xn  (mean path drops out: mask[0,0]=1 => K*const=const)
__global__ __launch_bounds__(256) void k_inv(const float* __restrict__ x,
                                             const float* __restrict__ gamma,
                                             const float* __restrict__ beta,
                                             const float2* __restrict__ msv,
                                             const float* __restrict__ m2s,
                                             const float* __restrict__ rscale,
                                             float* __restrict__ out) {
  __shared__ __half2 T[NH * 7 * CHT];  // y[i][{2jp,2jp+1}] fp16 pairs: 25KB
  __shared__ float2 ms[NTOK];
  __shared__ float wexp[NH];
  __shared__ float kc[NH];
  int b = blockIdx.y, c0 = blockIdx.x * CHT, tid = threadIdx.x;
  int c = tid & 63, w = tid >> 6;
  float rs = rscale[0];

  for (int k = tid; k < NTOK; k += 256) ms[k] = msv[b * NTOK + k];
  if (tid < CHT) {  // cls-token passthrough
    size_t idx = (size_t)b * NTOKP * NC + c0 + tid;
    out[idx] = x[idx];
  }
  float msb = m2s[b];
  if (tid < NH) {
    int f = (tid <= 7) ? tid : 14 - tid;
    wexp[tid] = __expf(-(float)(f * f) / msb);
  }
  __syncthreads();
  if (tid < NH) {
    float s = 0.f;
#pragma unroll
    for (int k = 0; k < NH; ++k) s = fmaf(wexp[k], CT14[(k * tid) % 14], s);
    kc[tid] = s * (1.f / 14.f);
  }
  float g = gamma[c0 + c], be = beta[c0 + c];
  __syncthreads();

  float kr[NH];
#pragma unroll
  for (int d = 0; d < NH; ++d) kr[d] = kc[d];
  // packed kernel-pair table: khp[d] = {kr[d], kr[(d+1)%14]}
  __half2 khp[NH];
#pragma unroll
  for (int d = 0; d < NH; ++d) khp[d] = __floats2half2_rn(kr[d], kr[(d + 1) % 14]);

  // stage 1: per (c,i): {y0,y1}[jp] = sum_j xn[i,j] * {kr[(2jp-j)%14], kr[(2jp+1-j)%14]}
#pragma unroll 1
  for (int i = w; i < NH; i += 4) {
    const float* xr = x + ((size_t)b * NTOKP + 1 + i * NH) * NC + c0 + c;
    __half2 xh[NH];
#pragma unroll
    for (int j = 0; j < NH; ++j) {
      float2 m = ms[i * NH + j];
      xh[j] = __float2half2_rn((xr[(size_t)j * NC] - m.x) * m.y * g + be);
    }
#pragma unroll
    for (int jp = 0; jp < 7; ++jp) {
      __half2 acc = __floats2half2_rn(0.f, 0.f);
#pragma unroll
      for (int j = 0; j < NH; ++j)
        acc = __hfma2(xh[j], khp[(2 * jp - j + 28) % 14], acc);
      T[(i * 7 + jp) * CHT + c] = acc;
    }
  }
  __syncthreads();

  // stage 2: per (c,jq): {z[2d],z[2d+1]} = sum_i y[i,jq] * khp[(2d-i)%14]
#pragma unroll 1
  for (int jq = w; jq < NH; jq += 4) {
    int jp = jq >> 1, hi = jq & 1;
    __half2 acc2[7];
#pragma unroll
    for (int d = 0; d < 7; ++d) acc2[d] = __floats2half2_rn(0.f, 0.f);
#pragma unroll
    for (int i = 0; i < NH; ++i) {
      __half2 t = T[(i * 7 + jp) * CHT + c];
      __half2 yi = hi ? __high2half2(t) : __low2half2(t);  // wave-uniform select
#pragma unroll
      for (int d = 0; d < 7; ++d)
        acc2[d] = __hfma2(yi, khp[(2 * d - i + 28) % 14], acc2[d]);
    }
    const float* xr = x + ((size_t)b * NTOKP + 1 + jq) * NC + c0 + c;
    float* outr = out + ((size_t)b * NTOKP + 1 + jq) * NC + c0 + c;
#pragma unroll
    for (int ii = 0; ii < NH; ++ii) {
      float z = (ii & 1) ? __high2float(acc2[ii >> 1]) : __low2float(acc2[ii >> 1]);
      float xv = xr[(size_t)ii * NH * NC];
      float2 m = ms[ii * NH + jq];
      float xn = (xv - m.x) * m.y * g + be;
      outr[(size_t)ii * NH * NC] = xv + rs * (z - xn);
    }
  }
}

extern "C" void kernel_launch(void* const* d_in, const int* in_sizes, int n_in,
                              void* d_out, int out_size, void* d_ws, size_t ws_size,
                              hipStream_t stream) {
  (void)in_sizes; (void)n_in; (void)out_size; (void)ws_size;
  const float* x      = (const float*)d_in[0];
  const float* gamma  = (const float*)d_in[1];
  const float* beta   = (const float*)d_in[2];
  const float* w1     = (const float*)d_in[3];
  const float* b1     = (const float*)d_in[4];
  const float* w2     = (const float*)d_in[5];
  const float* b2     = (const float*)d_in[6];
  const float* rscale = (const float*)d_in[7];
  float* out = (float*)d_out;

  char* wsb = (char*)d_ws;
  float2* msv    = (float2*)(wsb + 0);        //   401,408 B
  float* energy  = (float*)(wsb + 401408);    //   786,432 B  [NB][NC]
  float* partial = (float*)(wsb + 1187840);   // 1,572,864 B  [NB][NCH][NHID]
  float* m2s     = (float*)(wsb + 2760704);   //     1,024 B

  k_stats<<<(NB * NTOK + 3) / 4, 256, 0, stream>>>(x, msv);
  k_fwd<<<dim3(NTILE, NB), 256, 0, stream>>>(x, gamma, beta, msv, energy);
  k_mlp1<<<dim3(NCH, NB), 192, 0, stream>>>(energy, w1, partial);
  k_final<<<NB, 192, 0, stream>>>(partial, b1, w2, b2, m2s);
  k_inv<<<dim3(NTILE, NB), 256, 0, stream>>>(x, gamma, beta, msv, m2s, rscale,
                                             out);
}

// Round 11
// 144.388 us; speedup vs baseline: 1.6415x; 1.0670x over previous
//
#include <hip/hip_runtime.h>
#include <hip/hip_fp16.h>
#include <math.h>

// ---------------- problem constants ----------------
#define NB    256
#define NTOKP 197
#define NTOK  196
#define NC    768
#define NHID  192
#define NH    14
#define NVF   8        // rfft cols = 14/2+1
#define CHT   64       // channels per tile
#define NTILE 12       // 768/64
#define NCH   8        // C-chunks in k_mlp1
#define CCH   (NC / NCH)  // 96 channels per chunk

// twiddles (compile-time folded under full unroll)
constexpr float CT14[14] = {
    1.0f, 0.9009688679024191f, 0.6234898018587336f, 0.22252093395631445f,
    -0.22252093395631434f, -0.6234898018587335f, -0.9009688679024191f, -1.0f,
    -0.9009688679024191f, -0.6234898018587335f, -0.22252093395631434f,
    0.22252093395631445f, 0.6234898018587336f, 0.9009688679024191f};
constexpr float ST14[14] = {
    0.0f, 0.4338837391175581f, 0.7818314824680298f, 0.9749279121818236f,
    0.9749279121818236f, 0.7818314824680299f, 0.43388373911755823f, 0.0f,
    -0.43388373911755823f, -0.7818314824680299f, -0.9749279121818236f,
    -0.9749279121818236f, -0.7818314824680298f, -0.4338837391175581f};

// ---------------- K1: LayerNorm stats per (b, token) -> float2(mean, rstd) ----
__global__ __launch_bounds__(256) void k_stats(const float* __restrict__ x,
                                               float2* __restrict__ msv) {
  int row = blockIdx.x * 4 + (threadIdx.x >> 6);
  int lane = threadIdx.x & 63;
  if (row >= NB * NTOK) return;
  int b = row / NTOK, t = row - b * NTOK;
  const float4* p = (const float4*)(x + ((size_t)b * NTOKP + 1 + t) * NC);
  float s = 0.f, ss = 0.f;
#pragma unroll
  for (int k = 0; k < 3; ++k) {
    float4 v = p[lane + k * 64];
    s += v.x + v.y + v.z + v.w;
    ss += v.x * v.x + v.y * v.y + v.z * v.z + v.w * v.w;
  }
#pragma unroll
  for (int off = 32; off; off >>= 1) {
    s += __shfl_down(s, off);
    ss += __shfl_down(ss, off);
  }
  if (lane == 0) {
    float m = s * (1.f / NC);
    float var = ss * (1.f / NC) - m * m;
    msv[row] = make_float2(m, rsqrtf(var + 1e-5f));
  }
}

// ---------------- K2: forward DFT + energy (packed fp16, radix-2 stage B) ----
__global__ __launch_bounds__(256) void k_fwd(const float* __restrict__ x,
                                             const float* __restrict__ gamma,
                                             const float* __restrict__ beta,
                                             const float2* __restrict__ msv,
                                             float* __restrict__ energy) {
  __shared__ __half2 A[NH * NVF * CHT];  // [i][v][c] {re,im} fp16  28.7KB
  __shared__ float2 ms[NTOK];
  __shared__ float esum[256];
  int b = blockIdx.y, c0 = blockIdx.x * CHT, tid = threadIdx.x;
  int c = tid & 63, w = tid >> 6;

  for (int k = tid; k < NTOK; k += 256) ms[k] = msv[b * NTOK + k];
  float g = gamma[c0 + c], be = beta[c0 + c];

  // twiddle pair tables {cos,-sin}, {sin,cos}; omega7^t = omega14^(2t)
  __half2 TW1[14], TW2[14];
#pragma unroll
  for (int k = 0; k < 14; ++k) {
    TW1[k] = __floats2half2_rn(CT14[k], -ST14[k]);
    TW2[k] = __floats2half2_rn(ST14[k], CT14[k]);
  }
  __syncthreads();

  // stage A: per (c,i): A[i,v] = sum_j xn[i,j] e^{-2pi i v j/14}
#pragma unroll 1
  for (int i = w; i < NH; i += 4) {
    const float* xr = x + ((size_t)b * NTOKP + 1 + i * NH) * NC + c0 + c;
    __half2 xh[NH];
#pragma unroll
    for (int j = 0; j < NH; ++j) {
      float2 m = ms[i * NH + j];
      xh[j] = __float2half2_rn((xr[(size_t)j * NC] - m.x) * m.y * g + be);
    }
    __half2 acc[NVF];
#pragma unroll
    for (int v = 0; v < NVF; ++v) acc[v] = __floats2half2_rn(0.f, 0.f);
#pragma unroll
    for (int j = 0; j < NH; ++j) {
#pragma unroll
      for (int v = 0; v < NVF; ++v)
        acc[v] = __hfma2(xh[j], TW1[(v * j) % 14], acc[v]);
    }
#pragma unroll
    for (int v = 0; v < NVF; ++v) A[(i * NVF + v) * CHT + c] = acc[v];
  }
  __syncthreads();

  // stage B (radix-2 over i): S[u] = E[u%7] + w14^u * O[u%7]
  // energy via grouped logs: sum log1p(|S|/14) = log(prod(14+|S|)) - n*ln(14)
  float part = 0.f;
#pragma unroll 1
  for (int vv = 0; vv < 2; ++vv) {
    int v = w * 2 + vv;
    bool herm = (v == 0) || (v == 7);  // |S[14-u]| == |S[u]| in these columns
    const __half2* Ac = A + v * CHT + c;
    __half2 E[7], O[7];
#pragma unroll
    for (int k = 0; k < 7; ++k) {
      E[k] = __floats2half2_rn(0.f, 0.f);
      O[k] = __floats2half2_rn(0.f, 0.f);
    }
#pragma unroll
    for (int m = 0; m < 7; ++m) {
      __half2 ae = Ac[(2 * m) * NVF * CHT];
      __half2 ao = Ac[(2 * m + 1) * NVF * CHT];
      __half2 aer = __low2half2(ae), aei = __high2half2(ae);
      __half2 aor = __low2half2(ao), aoi = __high2half2(ao);
#pragma unroll
      for (int k = 0; k < 7; ++k) {
        int t = (2 * k * m) % 14;
        E[k] = __hfma2(aer, TW1[t], __hfma2(aei, TW2[t], E[k]));
        O[k] = __hfma2(aor, TW1[t], __hfma2(aoi, TW2[t], O[k]));
      }
    }
    float pa = 1.f, pb = 1.f;
#pragma unroll
    for (int u = 0; u < 14; ++u) {
      if (!herm || u < 8) {
        int k = u % 7;
        __half2 Ov = O[k];
        __half2 S = __hfma2(__low2half2(Ov), TW1[u],
                            __hfma2(__high2half2(Ov), TW2[u], E[k]));
        float2 s2 = __half22float2(S);
        float mag = 14.f + __builtin_amdgcn_sqrtf(fmaf(s2.x, s2.x, s2.y * s2.y));
        if (herm) {
          float msq = mag * mag;
          if (u == 0) {
            if (v == 7) pb *= mag;  // v==0,u==0 is DC: excluded
          } else if (u <= 3) {
            pa *= msq;              // u and 14-u counted together
          } else if (u <= 6) {
            pb *= msq;
          } else {
            pb *= mag;              // u==7 self-mirror
          }
        } else {
          if (u < 7) pa *= mag; else pb *= mag;
        }
      }
    }
    part += __logf(pa) + __logf(pb);
  }
  esum[tid] = part;
  __syncthreads();
  if (w == 0) {
    // 111 bins contributed per channel (112 minus DC); each carries -ln(14)
    float e = esum[c] + esum[c + 64] + esum[c + 128] + esum[c + 192];
    energy[(size_t)b * NC + c0 + c] =
        (e - 111.f * 2.6390573296152584f) * (1.f / 112.f);
  }
}

// ---------------- K3a: MLP layer-1 partials. 2048 blocks for TLP ----------------
__global__ __launch_bounds__(192) void k_mlp1(const float* __restrict__ energy,
                                              const float* __restrict__ w1,
                                              float* __restrict__ partial) {
  int s = blockIdx.x, b = blockIdx.y;
  int h = threadIdx.x;
  const float* ep = energy + (size_t)b * NC + s * CCH;
  const float* wp = w1 + (size_t)s * CCH * NHID + h;
  float acc = 0.f;
#pragma unroll 8
  for (int cc = 0; cc < CCH; ++cc)
    acc = fmaf(ep[cc], wp[(size_t)cc * NHID], acc);
  partial[((size_t)b * NCH + s) * NHID + h] = acc;
}

// ---------------- K3b: finalize MLP per batch ----------------
__global__ __launch_bounds__(192) void k_final(const float* __restrict__ partial,
                                               const float* __restrict__ b1,
                                               const float* __restrict__ w2,
                                               const float* __restrict__ b2,
                                               float* __restrict__ m2s) {
  __shared__ float2 sh[NHID];
  int b = blockIdx.x, h = threadIdx.x;
  float a = b1[h];
#pragma unroll
  for (int s = 0; s < NCH; ++s) a += partial[((size_t)b * NCH + s) * NHID + h];
  float ge = 0.5f * a * (1.f + erff(a * 0.70710678118654752f));  // exact gelu
  sh[h] = make_float2(ge * w2[2 * h], ge * w2[2 * h + 1]);
  __syncthreads();
  if (h < 64) {
    float p0 = sh[h].x + sh[h + 64].x + sh[h + 128].x;
    float p1 = sh[h].y + sh[h + 64].y + sh[h + 128].y;
#pragma unroll
    for (int off = 32; off; off >>= 1) {
      p0 += __shfl_down(p0, off);
      p1 += __shfl_down(p1, off);
    }
    if (h == 0) {
      float o0 = p0 + b2[0], o1 = p1 + b2[1];
      float muv = 9.899494936611665f / (1.f + expf(-o0));
      muv = fmaxf(muv, 1.f);
      float sp = (o1 > 20.f) ? o1 : log1pf(expf(o1));
      float sg = fmaxf(sp, 0.1f);
      m2s[b] = 2.f * muv * muv * sg + 1e-6f;
    }
  }
}

// ---------------- K4: separable circulant filter (packed fp16) + residual ----
// mask separable: exp(-(fy2[u]+fx2[v])/ms) = wexp[u]*wexp[v]
// filtered = K (x) K (x) xn  (mean path drops out: mask[0,0]=1 => K*const=const)
__global__ __launch_bounds__(256) void k_inv(const float* __restrict__ x,
                                             const float* __restrict__ gamma,
                                             const float* __restrict__ beta,
                                             const float2* __restrict__ msv,
                                             const float* __restrict__ m2s,
                                             const float* __restrict__ rscale,
                                             float* __restrict__ out) {
  __shared__ __half2 T[NH * 7 * CHT];  // y[i][{2jp,2jp+1}] fp16 pairs: 25KB
  __shared__ float2 ms[NTOK];
  __shared__ float wexp[NH];
  __shared__ float kc[NH];
  int b = blockIdx.y, c0 = blockIdx.x * CHT, tid = threadIdx.x;
  int c = tid & 63, w = tid >> 6;
  float rs = rscale[0];

  for (int k = tid; k < NTOK; k += 256) ms[k] = msv[b * NTOK + k];
  if (tid < CHT) {  // cls-token passthrough
    size_t idx = (size_t)b * NTOKP * NC + c0 + tid;
    out[idx] = x[idx];
  }
  float msb = m2s[b];
  if (tid < NH) {
    int f = (tid <= 7) ? tid : 14 - tid;
    wexp[tid] = __expf(-(float)(f * f) / msb);
  }
  __syncthreads();
  if (tid < NH) {
    float s = 0.f;
#pragma unroll
    for (int k = 0; k < NH; ++k) s = fmaf(wexp[k], CT14[(k * tid) % 14], s);
    kc[tid] = s * (1.f / 14.f);
  }
  float g = gamma[c0 + c], be = beta[c0 + c];
  __syncthreads();

  float kr[NH];
#pragma unroll
  for (int d = 0; d < NH; ++d) kr[d] = kc[d];
  // packed kernel-pair table: khp[d] = {kr[d], kr[(d+1)%14]}
  __half2 khp[NH];
#pragma unroll
  for (int d = 0; d < NH; ++d) khp[d] = __floats2half2_rn(kr[d], kr[(d + 1) % 14]);

  // stage 1: per (c,i): {y0,y1}[jp] = sum_j xn[i,j] * {kr[(2jp-j)%14], kr[(2jp+1-j)%14]}
#pragma unroll 1
  for (int i = w; i < NH; i += 4) {
    const float* xr = x + ((size_t)b * NTOKP + 1 + i * NH) * NC + c0 + c;
    __half2 xh[NH];
#pragma unroll
    for (int j = 0; j < NH; ++j) {
      float2 m = ms[i * NH + j];
      xh[j] = __float2half2_rn((xr[(size_t)j * NC] - m.x) * m.y * g + be);
    }
#pragma unroll
    for (int jp = 0; jp < 7; ++jp) {
      __half2 acc = __floats2half2_rn(0.f, 0.f);
#pragma unroll
      for (int j = 0; j < NH; ++j)
        acc = __hfma2(xh[j], khp[(2 * jp - j + 28) % 14], acc);
      T[(i * 7 + jp) * CHT + c] = acc;
    }
  }
  __syncthreads();

  // stage 2: per (c,jq): {z[2d],z[2d+1]} = sum_i y[i,jq] * khp[(2d-i)%14]
#pragma unroll 1
  for (int jq = w; jq < NH; jq += 4) {
    int jp = jq >> 1, hi = jq & 1;
    __half2 acc2[7];
#pragma unroll
    for (int d = 0; d < 7; ++d) acc2[d] = __floats2half2_rn(0.f, 0.f);
#pragma unroll
    for (int i = 0; i < NH; ++i) {
      __half2 t = T[(i * 7 + jp) * CHT + c];
      __half2 yi = hi ? __high2half2(t) : __low2half2(t);  // wave-uniform select
#pragma unroll
      for (int d = 0; d < 7; ++d)
        acc2[d] = __hfma2(yi, khp[(2 * d - i + 28) % 14], acc2[d]);
    }
    const float* xr = x + ((size_t)b * NTOKP + 1 + jq) * NC + c0 + c;
    float* outr = out + ((size_t)b * NTOKP + 1 + jq) * NC + c0 + c;
#pragma unroll
    for (int ii = 0; ii < NH; ++ii) {
      float z = (ii & 1) ? __high2float(acc2[ii >> 1]) : __low2float(acc2[ii >> 1]);
      float xv = xr[(size_t)ii * NH * NC];
      float2 m = ms[ii * NH + jq];
      float xn = (xv - m.x) * m.y * g + be;
      outr[(size_t)ii * NH * NC] = xv + rs * (z - xn);
    }
  }
}

extern "C" void kernel_launch(void* const* d_in, const int* in_sizes, int n_in,
                              void* d_out, int out_size, void* d_ws, size_t ws_size,
                              hipStream_t stream) {
  (void)in_sizes; (void)n_in; (void)out_size; (void)ws_size;
  const float* x      = (const float*)d_in[0];
  const float* gamma  = (const float*)d_in[1];
  const float* beta   = (const float*)d_in[2];
  const float* w1     = (const float*)d_in[3];
  const float* b1     = (const float*)d_in[4];
  const float* w2     = (const float*)d_in[5];
  const float* b2     = (const float*)d_in[6];
  const float* rscale = (const float*)d_in[7];
  float* out = (float*)d_out;

  char* wsb = (char*)d_ws;
  float2* msv    = (float2*)(wsb + 0);        //   401,408 B
  float* energy  = (float*)(wsb + 401408);    //   786,432 B  [NB][NC]
  float* partial = (float*)(wsb + 1187840);   // 1,572,864 B  [NB][NCH][NHID]
  float* m2s     = (float*)(wsb + 2760704);   //     1,024 B

  k_stats<<<(NB * NTOK + 3) / 4, 256, 0, stream>>>(x, msv);
  k_fwd<<<dim3(NTILE, NB), 256, 0, stream>>>(x, gamma, beta, msv, energy);
  k_mlp1<<<dim3(NCH, NB), 192, 0, stream>>>(energy, w1, partial);
  k_final<<<NB, 192, 0, stream>>>(partial, b1, w2, b2, m2s);
  k_inv<<<dim3(NTILE, NB), 256, 0, stream>>>(x, gamma, beta, msv, m2s, rscale,
                                             out);
}